// Round 10
// baseline (326.709 us; speedup 1.0000x reference)
//
#include <hip/hip_runtime.h>
#include <hip/hip_bf16.h>

using bf16 = __hip_bfloat16;
typedef __attribute__((ext_vector_type(8))) short short8;
typedef __attribute__((ext_vector_type(4))) float f32x4;

constexpr int NLAYER = 2;
constexpr int NB = 2;
constexpr int NS = 1024;
constexpr int ND = 512;
constexpr int NH = 32;
constexpr int NF = 2048;
constexpr int NC = 1000;
constexpr float EPS_LN = 1e-5f;

__device__ inline unsigned short f2bfu(float x) {
    union { bf16 h; unsigned short u; } c;
    c.h = __float2bfloat16(x);
    return c.u;
}

#define GLOAD16(gp, lp) __builtin_amdgcn_global_load_lds( \
    (const __attribute__((address_space(1))) void*)(gp),  \
    (__attribute__((address_space(3))) void*)(lp), 16, 0, 0)

// ---------------------------------------------------------------------------
// bf16 MFMA GEMM, C = A[MxK] * B^T[NxK] (+bias) (+ReLU | scores | V^T-write)
// 512 thr / 8 waves (WR x WC), BK=64, TRIPLE-buffered LDS, depth-2 prefetch:
//   prologue: stage(0), stage(1)            [2*SW outstanding]
//   step t: wait vmcnt(SW if t+1<nt else 0) -> barrier -> issue stage(t+2)
//           -> compute tile t -> barrier
// Each tile's loads get ~2 K-steps of latency cover (HBM ~900cy, L2 ~200cy).
// LDS chunk = 8 rows x 64 k (1024B), XOR-swizzled (T2) on source + read side.
// ---------------------------------------------------------------------------
template<int BM, int BN, int WR, int WC, bool OUTBF, bool RELU, bool SCORES, bool VOUT>
__global__ __launch_bounds__(512) void mfma_gemm(
    const bf16* __restrict__ A, const bf16* __restrict__ B,
    const float* __restrict__ bias, void* __restrict__ Cout,
    const float* __restrict__ table, bf16* __restrict__ vT,
    int K, int lda, int ldb, int ldc,
    long sA, long sB, long sC, float alpha)
{
    const int bz = blockIdx.z;
    A += (long)bz * sA;
    B += (long)bz * sB;
    const int bm = blockIdx.y * BM, bn = blockIdx.x * BN;
    __shared__ bf16 As[3][BM * 64], Bs[3][BN * 64];
    const int tid = threadIdx.x, lane = tid & 63, wv = tid >> 6;
    constexpr int WM = BM / WR, WN = BN / WC;
    constexpr int FM = WM / 16, FN = WN / 16;
    const int wr = (wv / WC) * WM, wc = (wv % WC) * WN;
    f32x4 acc[FM][FN] = {};
    const int krow = lane >> 3;                   // row within 8-row chunk
    const int ko = ((lane & 7) ^ krow) * 8;       // swizzled k-group (T2 XOR)
    constexpr int ACH = BM / 8, NCH = (BM + BN) / 8;
    constexpr int SW = NCH / 8;                   // loads/thread/stage (uniform)

    auto stage = [&](int buf, int k0) {
        #pragma unroll
        for (int i = 0; i < SW; ++i) {
            const int c = wv + i * 8;
            if (c < ACH)
                GLOAD16(A + (long)(bm + c * 8 + krow) * lda + k0 + ko,
                        &As[buf][c * 512]);
            else
                GLOAD16(B + (long)(bn + (c - ACH) * 8 + krow) * ldb + k0 + ko,
                        &Bs[buf][(c - ACH) * 512]);
        }
    };

    const int nt = K >> 6;
    stage(0, 0);
    stage(1, 64);

    const int rq = lane & 7;                      // row-within-chunk on read side
    int cur = 0;
    for (int t = 0; t < nt; ++t) {
        if (t + 1 < nt) {
            if constexpr (SW == 2)      asm volatile("s_waitcnt vmcnt(2)" ::: "memory");
            else if constexpr (SW == 3) asm volatile("s_waitcnt vmcnt(3)" ::: "memory");
            else                        asm volatile("s_waitcnt vmcnt(4)" ::: "memory");
        } else {
            asm volatile("s_waitcnt vmcnt(0)" ::: "memory");
        }
        __builtin_amdgcn_sched_barrier(0);
        __builtin_amdgcn_s_barrier();   // tile t fully landed for all waves

        if (t + 2 < nt) {
            int nb = cur + 2; if (nb >= 3) nb -= 3;
            stage(nb, (t + 2) << 6);
        }

        const short8* Asv = (const short8*)As[cur];
        const short8* Bsv = (const short8*)Bs[cur];
        #pragma unroll
        for (int ks = 0; ks < 2; ++ks) {
            short8 af[FM], bfr[FN];
            #pragma unroll
            for (int m = 0; m < FM; ++m) {
                const int row = wr + m * 16 + (lane & 15);
                af[m] = Asv[(row >> 3) * 64 + rq * 8 + ((ks * 4 + (lane >> 4)) ^ rq)];
            }
            #pragma unroll
            for (int n = 0; n < FN; ++n) {
                const int row = wc + n * 16 + (lane & 15);
                bfr[n] = Bsv[(row >> 3) * 64 + rq * 8 + ((ks * 4 + (lane >> 4)) ^ rq)];
            }
            #pragma unroll
            for (int m = 0; m < FM; ++m)
                #pragma unroll
                for (int n = 0; n < FN; ++n)
                    acc[m][n] = __builtin_amdgcn_mfma_f32_16x16x32_bf16(
                        af[m], bfr[n], acc[m][n], 0, 0, 0);
        }
        __builtin_amdgcn_s_barrier();   // all waves done reading cur before overwrite
        if (++cur >= 3) cur = 0;
    }

    const int er = (lane >> 4) * 4, ec = lane & 15;
    #pragma unroll
    for (int m = 0; m < FM; ++m) {
        #pragma unroll
        for (int n = 0; n < FN; ++n) {
            const int row0 = bm + wr + m * 16 + er;
            const int col  = bn + wc + n * 16 + ec;
            const float bv = bias ? bias[col] : 0.f;
            #pragma unroll
            for (int e = 0; e < 4; ++e) {
                const int row = row0 + e;
                float v = acc[m][n][e];
                if (SCORES) {
                    int di = (col >> 5) - (row >> 5) + 31;
                    int dj = (col & 31) - (row & 31) + 31;
                    v = v * alpha + table[di * 63 + dj];
                } else {
                    v += bv;
                    if (RELU) v = fmaxf(v, 0.f);
                }
                if (OUTBF)
                    ((bf16*)Cout)[bz * sC + (long)row * ldc + col] = __float2bfloat16(v);
                else
                    ((float*)Cout)[bz * sC + (long)row * ldc + col] = v;
                if (VOUT && col >= 2 * ND) {
                    int bb = row >> 10;
                    vT[(long)bb * ND * NS + (long)(col - 2 * ND) * NS + (row & (NS - 1))] =
                        __float2bfloat16(v);
                }
            }
        }
    }
}

// ---------------------------------------------------------------------------
// Merged prep: [0,5632) weight transposes; [5632,6656) xcopy;
// [6656,6672) bias table; [6672,6684) out/pooled init.
// ---------------------------------------------------------------------------
__global__ __launch_bounds__(256) void prep_kernel(
    const float* __restrict__ Wq, const float* __restrict__ Wk,
    const float* __restrict__ Wv, const float* __restrict__ ffn_w1,
    const float* __restrict__ ffn_w2, bf16* __restrict__ wqkvT,
    bf16* __restrict__ w1T, bf16* __restrict__ w2T,
    const float* __restrict__ xin, float* __restrict__ xc, bf16* __restrict__ xb,
    const float* __restrict__ coords,
    const float* __restrict__ rot_w1, const float* __restrict__ rot_b1,
    const float* __restrict__ rot_w2, const float* __restrict__ rot_b2,
    const float* __restrict__ trans_w1, const float* __restrict__ trans_b1,
    const float* __restrict__ trans_w2, const float* __restrict__ trans_b2,
    const float* __restrict__ refl_w1, const float* __restrict__ refl_b1,
    const float* __restrict__ refl_w2, const float* __restrict__ refl_b2,
    float* __restrict__ table,
    const float* __restrict__ fc_b, float* __restrict__ out,
    float* __restrict__ pooled)
{
    const int blk = blockIdx.x, tid = threadIdx.x;
    if (blk < 5632) {
        const int s = blk;
        const float* src; bf16* dst; int R, C, r0, c0;
        if (s < 1536) {
            int z = s >> 8, rem = s & 255;
            int l = z / 3, wsel = z % 3;
            src = (wsel == 0 ? Wq : wsel == 1 ? Wk : Wv) + (long)l * ND * ND;
            dst = wqkvT + (long)l * 3 * ND * ND + (long)wsel * ND * ND;
            R = ND; C = ND; c0 = (rem & 15) * 32; r0 = (rem >> 4) * 32;
        } else if (s < 3584) {
            int t = s - 1536, l = t >> 10, rem = t & 1023;
            src = ffn_w1 + (long)l * ND * NF;
            dst = w1T + (long)l * NF * ND;
            R = ND; C = NF; c0 = (rem & 63) * 32; r0 = (rem >> 6) * 32;
        } else {
            int t = s - 3584, l = t >> 10, rem = t & 1023;
            src = ffn_w2 + (long)l * NF * ND;
            dst = w2T + (long)l * ND * NF;
            R = NF; C = ND; c0 = (rem & 15) * 32; r0 = (rem >> 4) * 32;
        }
        __shared__ float t[32][33];
        const int lx = tid & 31, ly = tid >> 5;
        for (int rr = ly; rr < 32; rr += 8)
            t[rr][lx] = src[(long)(r0 + rr) * C + c0 + lx];
        __syncthreads();
        for (int cc = ly; cc < 32; cc += 8)
            dst[(long)(c0 + cc) * R + r0 + lx] = __float2bfloat16(t[lx][cc]);
        return;
    }
    if (blk < 6656) {
        long i = (long)(blk - 5632) * 256 + tid;
        float4 v = ((const float4*)xin)[i];
        ((float4*)xc)[i] = v;
        uint2 o;
        o.x = (unsigned)f2bfu(v.x) | ((unsigned)f2bfu(v.y) << 16);
        o.y = (unsigned)f2bfu(v.z) | ((unsigned)f2bfu(v.w) << 16);
        ((uint2*)xb)[i] = o;
        return;
    }
    if (blk < 6672) {
        int idx = (blk - 6656) * 256 + tid;
        if (idx >= 63 * 63) return;
        int da = idx / 63 - 31, db = idx % 63 - 31;
        int ai = da < 0 ? -da : 0, bi = db < 0 ? -db : 0;
        int i = ai * 32 + bi, j = (ai + da) * 32 + (bi + db);
        float2 ci = ((const float2*)coords)[i];
        float2 cj = ((const float2*)coords)[j];
        float dx = cj.x - ci.x, dy = cj.y - ci.y;
        float dist = sqrtf(dx * dx + dy * dy + 1e-8f);
        float th = atan2f(dy, dx);
        float sn = sinf(th), cs = cosf(th);
        #pragma unroll
        for (int l = 0; l < NLAYER; ++l) {
            const float* rw1 = rot_w1 + l * 3 * NH;
            const float* rb1 = rot_b1 + l * NH;
            const float* rw2 = rot_w2 + l * NH;
            const float* tw1 = trans_w1 + l * 2 * NH;
            const float* tb1 = trans_b1 + l * NH;
            const float* tw2 = trans_w2 + l * NH;
            const float* fw1 = refl_w1 + l * 4 * NH;
            const float* fb1 = refl_b1 + l * NH;
            const float* fw2 = refl_w2 + l * NH;
            float acc = rot_b2[l] + trans_b2[l] + refl_b2[l];
            #pragma unroll 8
            for (int h = 0; h < NH; ++h) {
                float hr = fmaxf(dist * rw1[h] + sn * rw1[NH + h] + cs * rw1[2 * NH + h] + rb1[h], 0.f);
                acc += hr * rw2[h];
                float ht = fmaxf(dx * tw1[h] + dy * tw1[NH + h] + tb1[h], 0.f);
                acc += ht * tw2[h];
                float hf = fmaxf(dx * fw1[h] + dy * fw1[NH + h] - dx * fw1[2 * NH + h] - dy * fw1[3 * NH + h] + fb1[h], 0.f);
                acc += hf * fw2[h];
            }
            table[l * 3969 + idx] = acc;
        }
        return;
    }
    {
        int i = (blk - 6672) * 256 + tid;
        if (i < NB * NC) out[i] = fc_b[i % NC];
        int j = i - NB * NC;
        if (j >= 0 && j < NB * ND) pooled[j] = 0.f;
    }
}

// ---------------------------------------------------------------------------
// Row softmax over NS=1024 (f32 in) -> bf16 out
// ---------------------------------------------------------------------------
__global__ __launch_bounds__(256) void softmax_kernel(
    const float* __restrict__ sc, bf16* __restrict__ P)
{
    const float* p = sc + (long)blockIdx.x * NS;
    const int tid = threadIdx.x;
    float4 v = ((const float4*)p)[tid];
    float m = fmaxf(fmaxf(v.x, v.y), fmaxf(v.z, v.w));
    #pragma unroll
    for (int off = 32; off; off >>= 1) m = fmaxf(m, __shfl_xor(m, off));
    __shared__ float red[4], red2[4];
    int wid = tid >> 6;
    if ((tid & 63) == 0) red[wid] = m;
    __syncthreads();
    m = fmaxf(fmaxf(red[0], red[1]), fmaxf(red[2], red[3]));
    v.x = __expf(v.x - m); v.y = __expf(v.y - m);
    v.z = __expf(v.z - m); v.w = __expf(v.w - m);
    float s = v.x + v.y + v.z + v.w;
    #pragma unroll
    for (int off = 32; off; off >>= 1) s += __shfl_xor(s, off);
    if ((tid & 63) == 0) red2[wid] = s;
    __syncthreads();
    s = red2[0] + red2[1] + red2[2] + red2[3];
    float inv = 1.f / s;
    uint2 o;
    o.x = (unsigned)f2bfu(v.x * inv) | ((unsigned)f2bfu(v.y * inv) << 16);
    o.y = (unsigned)f2bfu(v.z * inv) | ((unsigned)f2bfu(v.w * inv) << 16);
    ((uint2*)(P + (long)blockIdx.x * NS))[tid] = o;
}

// ---------------------------------------------------------------------------
// out = LayerNorm(x (+res)); also writes bf16 copy if outb != null
// ---------------------------------------------------------------------------
__global__ __launch_bounds__(256) void add_ln_kernel(
    const float* __restrict__ x, const float* __restrict__ res,
    const float* __restrict__ g, const float* __restrict__ bt,
    float* __restrict__ out, bf16* __restrict__ outb)
{
    long row = blockIdx.x;
    const int tid = threadIdx.x;
    float2 xv = ((const float2*)(x + row * ND))[tid];
    if (res) {
        float2 rv = ((const float2*)(res + row * ND))[tid];
        xv.x += rv.x; xv.y += rv.y;
    }
    float s = xv.x + xv.y;
    float ss = xv.x * xv.x + xv.y * xv.y;
    #pragma unroll
    for (int off = 32; off; off >>= 1) {
        s += __shfl_xor(s, off);
        ss += __shfl_xor(ss, off);
    }
    __shared__ float rs[4], rss[4];
    int wid = tid >> 6;
    if ((tid & 63) == 0) { rs[wid] = s; rss[wid] = ss; }
    __syncthreads();
    s = rs[0] + rs[1] + rs[2] + rs[3];
    ss = rss[0] + rss[1] + rss[2] + rss[3];
    float mu = s * (1.f / ND);
    float var = ss * (1.f / ND) - mu * mu;
    float inv = rsqrtf(var + EPS_LN);
    float2 gv = ((const float2*)g)[tid];
    float2 bv = ((const float2*)bt)[tid];
    float2 o;
    o.x = (xv.x - mu) * inv * gv.x + bv.x;
    o.y = (xv.y - mu) * inv * gv.y + bv.y;
    ((float2*)(out + row * ND))[tid] = o;
    if (outb)
        ((unsigned int*)(outb + row * ND))[tid] =
            (unsigned)f2bfu(o.x) | ((unsigned)f2bfu(o.y) << 16);
}

// ---------------------------------------------------------------------------
// pooled[b][d] += sum over 16 contiguous rows / NS; 128 blocks, atomics.
// ---------------------------------------------------------------------------
__global__ __launch_bounds__(256) void pool_kernel(
    const float* __restrict__ x, float* __restrict__ pooled)
{
    const int tid = threadIdx.x;
    const long row0 = (long)blockIdx.x * 16;
    const int b = (int)(row0 >> 10);
    float ax = 0.f, ay = 0.f, az = 0.f, aw = 0.f;
    #pragma unroll
    for (int it = 0; it < 8; ++it) {
        long r = row0 + it * 2 + (tid >> 7);
        float4 v = ((const float4*)(x + r * ND))[tid & 127];
        ax += v.x; ay += v.y; az += v.z; aw += v.w;
    }
    __shared__ float red[256][4];
    red[tid][0] = ax; red[tid][1] = ay; red[tid][2] = az; red[tid][3] = aw;
    __syncthreads();
    if (tid < 128) {
        int d = tid * 4;
        atomicAdd(&pooled[b * ND + d + 0], (red[tid][0] + red[tid + 128][0]) * (1.f / NS));
        atomicAdd(&pooled[b * ND + d + 1], (red[tid][1] + red[tid + 128][1]) * (1.f / NS));
        atomicAdd(&pooled[b * ND + d + 2], (red[tid][2] + red[tid + 128][2]) * (1.f / NS));
        atomicAdd(&pooled[b * ND + d + 3], (red[tid][3] + red[tid + 128][3]) * (1.f / NS));
    }
}

// ---------------------------------------------------------------------------
// out[b][c] += partial dot over 64-wide d-chunk; grid (16, NB, 8), atomics.
// ---------------------------------------------------------------------------
__global__ __launch_bounds__(256) void fc_kernel(
    const float* __restrict__ pooled, const float* __restrict__ w,
    float* __restrict__ out)
{
    const int lane = threadIdx.x & 63, dg = threadIdx.x >> 6;
    const int c = blockIdx.x * 64 + lane;
    const int b = blockIdx.y;
    const int d0 = blockIdx.z * 64 + dg * 16;
    const bool ok = (c < NC);
    const float* p = pooled + b * ND;
    float acc = 0.f;
    #pragma unroll
    for (int d = 0; d < 16; ++d)
        acc += p[d0 + d] * (ok ? w[(long)(d0 + d) * NC + c] : 0.f);
    __shared__ float red[4][64];
    red[dg][lane] = acc;
    __syncthreads();
    if (dg == 0 && ok)
        atomicAdd(&out[(long)b * NC + c],
                  red[0][lane] + red[1][lane] + red[2][lane] + red[3][lane]);
}

// ---------------------------------------------------------------------------
extern "C" void kernel_launch(void* const* d_in, const int* in_sizes, int n_in,
                              void* d_out, int out_size, void* d_ws, size_t ws_size,
                              hipStream_t stream)
{
    const float* x_in   = (const float*)d_in[0];
    const float* coords = (const float*)d_in[1];
    const float* Wq     = (const float*)d_in[2];
    const float* Wk     = (const float*)d_in[3];
    const float* Wv     = (const float*)d_in[4];
    const float* rot_w1 = (const float*)d_in[5];
    const float* rot_b1 = (const float*)d_in[6];
    const float* rot_w2 = (const float*)d_in[7];
    const float* rot_b2 = (const float*)d_in[8];
    const float* trans_w1 = (const float*)d_in[9];
    const float* trans_b1 = (const float*)d_in[10];
    const float* trans_w2 = (const float*)d_in[11];
    const float* trans_b2 = (const float*)d_in[12];
    const float* refl_w1 = (const float*)d_in[13];
    const float* refl_b1 = (const float*)d_in[14];
    const float* refl_w2 = (const float*)d_in[15];
    const float* refl_b2 = (const float*)d_in[16];
    const float* ln1_g = (const float*)d_in[17];
    const float* ln1_b = (const float*)d_in[18];
    const float* ffn_w1 = (const float*)d_in[19];
    const float* ffn_b1 = (const float*)d_in[20];
    const float* ffn_w2 = (const float*)d_in[21];
    const float* ffn_b2 = (const float*)d_in[22];
    const float* ln2_g = (const float*)d_in[23];
    const float* ln2_b = (const float*)d_in[24];
    const float* lnf_g = (const float*)d_in[25];
    const float* lnf_b = (const float*)d_in[26];
    const float* fc_w = (const float*)d_in[27];
    const float* fc_b = (const float*)d_in[28];
    float* out = (float*)d_out;

    const long XSZ = (long)NB * NS * ND;
    const long SSZ = (long)NB * NS * NS;

    char* wp = (char*)d_ws;
    auto alloc = [&](long bytes) -> char* {
        char* p = wp; wp += (bytes + 255) & ~(long)255; return p;
    };
    float* x_cur  = (float*)alloc(XSZ * 4);
    bf16*  xb     = (bf16*)alloc(XSZ * 2);
    bf16*  qkv    = (bf16*)alloc((long)NB * NS * 1536 * 2);
    bf16*  vT     = (bf16*)alloc((long)NB * ND * NS * 2);
    float* sc     = (float*)alloc(SSZ * 4);
    bf16*  pb     = (bf16*)alloc(SSZ * 2);
    float* ao     = (float*)alloc(XSZ * 4);
    bf16*  hfb    = (bf16*)alloc((long)NB * NS * NF * 2);
    bf16*  wqkvT  = (bf16*)alloc((long)NLAYER * 3 * ND * ND * 2);
    bf16*  w1T    = (bf16*)alloc((long)NLAYER * NF * ND * 2);
    bf16*  w2T    = (bf16*)alloc((long)NLAYER * ND * NF * 2);
    float* table  = (float*)alloc((long)NLAYER * 3969 * 4);
    float* pooled = (float*)alloc((long)NB * ND * 4);

    const float inv_scale = 1.0f / sqrtf((float)ND);
    const long QKVLD = 1536;

    prep_kernel<<<dim3(6684), 256, 0, stream>>>(
        Wq, Wk, Wv, ffn_w1, ffn_w2, wqkvT, w1T, w2T,
        x_in, x_cur, xb, coords,
        rot_w1, rot_b1, rot_w2, rot_b2,
        trans_w1, trans_b1, trans_w2, trans_b2,
        refl_w1, refl_b1, refl_w2, refl_b2, table,
        fc_b, out, pooled);

    for (int l = 0; l < NLAYER; ++l) {
        // QKV: [2048,512]@[1536,512]^T -> qkv bf16 (V cols also -> vT)
        mfma_gemm<64, 128, 2, 4, true, false, false, true>
            <<<dim3(1536 / 128, (NB * NS) / 64, 1), 512, 0, stream>>>(
            xb, wqkvT + (long)l * 3 * ND * ND, nullptr, qkv, nullptr, vT,
            ND, ND, ND, QKVLD, 0, 0, 0, 0.f);

        // scores = QK^T * inv_scale + table -> f32
        mfma_gemm<64, 128, 2, 4, false, false, true, false>
            <<<dim3(NS / 128, NS / 64, NB), 512, 0, stream>>>(
            qkv, qkv + ND, nullptr, sc, table + (long)l * 3969, nullptr,
            ND, QKVLD, QKVLD, NS, (long)NS * QKVLD, (long)NS * QKVLD,
            (long)NS * NS, inv_scale);

        softmax_kernel<<<dim3(NB * NS), 256, 0, stream>>>(sc, pb);

        // attn_out = P @ V
        mfma_gemm<64, 64, 4, 2, false, false, false, false>
            <<<dim3(ND / 64, NS / 64, NB), 512, 0, stream>>>(
            pb, vT, nullptr, ao, nullptr, nullptr,
            NS, NS, NS, ND, (long)NS * NS, (long)ND * NS, (long)NS * ND, 0.f);

        add_ln_kernel<<<dim3(NB * NS), 256, 0, stream>>>(
            x_cur, ao, ln1_g + (long)l * ND, ln1_b + (long)l * ND, x_cur, xb);

        // FFN1
        mfma_gemm<128, 128, 4, 2, true, true, false, false>
            <<<dim3(NF / 128, (NB * NS) / 128, 1), 512, 0, stream>>>(
            xb, w1T + (long)l * NF * ND, ffn_b1 + (long)l * NF, hfb, nullptr, nullptr,
            ND, ND, ND, NF, 0, 0, 0, 0.f);

        // FFN2
        mfma_gemm<64, 64, 4, 2, false, false, false, false>
            <<<dim3(ND / 64, (NB * NS) / 64, 1), 512, 0, stream>>>(
            hfb, w2T + (long)l * ND * NF, ffn_b2 + (long)l * ND, ao, nullptr, nullptr,
            NF, NF, NF, ND, 0, 0, 0, 0.f);

        add_ln_kernel<<<dim3(NB * NS), 256, 0, stream>>>(
            x_cur, ao, ln2_g + (long)l * ND, ln2_b + (long)l * ND, x_cur, xb);
    }

    add_ln_kernel<<<dim3(NB * NS), 256, 0, stream>>>(
        x_cur, nullptr, lnf_g, lnf_b, x_cur, nullptr);

    pool_kernel<<<dim3((NB * NS) / 16), 256, 0, stream>>>(x_cur, pooled);

    fc_kernel<<<dim3((NC + 63) / 64, NB, ND / 64), 256, 0, stream>>>(pooled, fc_w, out);
}

// Round 12
// 317.611 us; speedup vs baseline: 1.0286x; 1.0286x over previous
//
#include <hip/hip_runtime.h>
#include <hip/hip_bf16.h>

using bf16 = __hip_bfloat16;
typedef __attribute__((ext_vector_type(8))) short short8;
typedef __attribute__((ext_vector_type(4))) float f32x4;

constexpr int NLAYER = 2;
constexpr int NB = 2;
constexpr int NS = 1024;
constexpr int ND = 512;
constexpr int NH = 32;
constexpr int NF = 2048;
constexpr int NC = 1000;
constexpr float EPS_LN = 1e-5f;

__device__ inline unsigned f2bfu(float x) {
    union { bf16 h; unsigned short u; } c;
    c.h = __float2bfloat16(x);
    return (unsigned)c.u;
}

#define GLOAD16(gp, lp) __builtin_amdgcn_global_load_lds( \
    (const __attribute__((address_space(1))) void*)(gp),  \
    (__attribute__((address_space(3))) void*)(lp), 16, 0, 0)

// ---------------------------------------------------------------------------
// bf16 MFMA GEMM, C = A[MxK] * B^T[NxK] (+bias) (+ReLU | scores | V^T-write)
// 512 thr / 8 waves (WR x WC), BK=64, double-buffered LDS, counted-vmcnt
// pipeline (T3/T4-min, depth-1 -- R9 structure; depth-2 measured neutral).
// LDS chunk = 8 rows x 64 k (1024B), XOR-swizzled (T2) on source + read side.
// ---------------------------------------------------------------------------
template<int BM, int BN, int WR, int WC, bool OUTBF, bool RELU, bool SCORES, bool VOUT>
__global__ __launch_bounds__(512) void mfma_gemm(
    const bf16* __restrict__ A, const bf16* __restrict__ B,
    const float* __restrict__ bias, void* __restrict__ Cout,
    const float* __restrict__ table, bf16* __restrict__ vT,
    int K, int lda, int ldb, int ldc,
    long sA, long sB, long sC, float alpha)
{
    const int bz = blockIdx.z;
    A += (long)bz * sA;
    B += (long)bz * sB;
    const int bm = blockIdx.y * BM, bn = blockIdx.x * BN;
    __shared__ bf16 As[2][BM * 64], Bs[2][BN * 64];
    const int tid = threadIdx.x, lane = tid & 63, wv = tid >> 6;
    constexpr int WM = BM / WR, WN = BN / WC;
    constexpr int FM = WM / 16, FN = WN / 16;
    const int wr = (wv / WC) * WM, wc = (wv % WC) * WN;
    f32x4 acc[FM][FN] = {};
    const int krow = lane >> 3;                   // row within 8-row chunk
    const int ko = ((lane & 7) ^ krow) * 8;       // swizzled k-group (T2 XOR)
    constexpr int ACH = BM / 8, NCH = (BM + BN) / 8;
    constexpr int SW = NCH / 8;                   // loads/thread/stage (uniform)

    auto stage = [&](int buf, int k0) {
        #pragma unroll
        for (int i = 0; i < SW; ++i) {
            const int c = wv + i * 8;
            if (c < ACH)
                GLOAD16(A + (long)(bm + c * 8 + krow) * lda + k0 + ko,
                        &As[buf][c * 512]);
            else
                GLOAD16(B + (long)(bn + (c - ACH) * 8 + krow) * ldb + k0 + ko,
                        &Bs[buf][(c - ACH) * 512]);
        }
    };

    const int nt = K >> 6;
    stage(0, 0);
    asm volatile("s_waitcnt vmcnt(0)" ::: "memory");
    __builtin_amdgcn_sched_barrier(0);
    __builtin_amdgcn_s_barrier();

    const int rq = lane & 7;                      // row-within-chunk on read side
    for (int t = 0; t < nt; ++t) {
        const int cur = t & 1;
        if (t + 1 < nt) {
            stage(cur ^ 1, (t + 1) << 6);
            if constexpr (SW == 2)      asm volatile("s_waitcnt vmcnt(2)" ::: "memory");
            else if constexpr (SW == 3) asm volatile("s_waitcnt vmcnt(3)" ::: "memory");
            else                        asm volatile("s_waitcnt vmcnt(4)" ::: "memory");
        } else {
            asm volatile("s_waitcnt vmcnt(0)" ::: "memory");
        }
        __builtin_amdgcn_sched_barrier(0);
        __builtin_amdgcn_s_barrier();   // cur buffer fully landed for all waves

        const short8* Asv = (const short8*)As[cur];
        const short8* Bsv = (const short8*)Bs[cur];
        #pragma unroll
        for (int ks = 0; ks < 2; ++ks) {
            short8 af[FM], bfr[FN];
            #pragma unroll
            for (int m = 0; m < FM; ++m) {
                const int row = wr + m * 16 + (lane & 15);
                af[m] = Asv[(row >> 3) * 64 + rq * 8 + ((ks * 4 + (lane >> 4)) ^ rq)];
            }
            #pragma unroll
            for (int n = 0; n < FN; ++n) {
                const int row = wc + n * 16 + (lane & 15);
                bfr[n] = Bsv[(row >> 3) * 64 + rq * 8 + ((ks * 4 + (lane >> 4)) ^ rq)];
            }
            #pragma unroll
            for (int m = 0; m < FM; ++m)
                #pragma unroll
                for (int n = 0; n < FN; ++n)
                    acc[m][n] = __builtin_amdgcn_mfma_f32_16x16x32_bf16(
                        af[m], bfr[n], acc[m][n], 0, 0, 0);
        }
        __builtin_amdgcn_s_barrier();   // all waves done reading cur before overwrite
    }

    const int er = (lane >> 4) * 4, ec = lane & 15;
    #pragma unroll
    for (int m = 0; m < FM; ++m) {
        #pragma unroll
        for (int n = 0; n < FN; ++n) {
            const int row0 = bm + wr + m * 16 + er;
            const int col  = bn + wc + n * 16 + ec;
            const float bv = bias ? bias[col] : 0.f;
            #pragma unroll
            for (int e = 0; e < 4; ++e) {
                const int row = row0 + e;
                float v = acc[m][n][e];
                if (SCORES) {
                    int di = (col >> 5) - (row >> 5) + 31;
                    int dj = (col & 31) - (row & 31) + 31;
                    v = v * alpha + table[di * 63 + dj];
                } else {
                    v += bv;
                    if (RELU) v = fmaxf(v, 0.f);
                }
                if (OUTBF)
                    ((bf16*)Cout)[bz * sC + (long)row * ldc + col] = __float2bfloat16(v);
                else
                    ((float*)Cout)[bz * sC + (long)row * ldc + col] = v;
                if (VOUT && col >= 2 * ND) {
                    int bb = row >> 10;
                    vT[(long)bb * ND * NS + (long)(col - 2 * ND) * NS + (row & (NS - 1))] =
                        __float2bfloat16(v);
                }
            }
        }
    }
}

// ---------------------------------------------------------------------------
// Merged prep. Blocks:
//   [0,1408)    : 64x64 transpose+convert tiles (vectorized: float4 loads,
//                 LDS [64][65], uint2 (4xbf16) stores)
//                 [0,384) qkv | [384,896) ffn_w1 | [896,1408) ffn_w2
//   [1408,2432) : xcopy (x_in -> x_cur f32 + xb bf16)
//   [2432,2448) : 63x63 pair-bias table
//   [2448,2460) : out=fc_b init, pooled=0
// ---------------------------------------------------------------------------
__global__ __launch_bounds__(256) void prep_kernel(
    const float* __restrict__ Wq, const float* __restrict__ Wk,
    const float* __restrict__ Wv, const float* __restrict__ ffn_w1,
    const float* __restrict__ ffn_w2, bf16* __restrict__ wqkvT,
    bf16* __restrict__ w1T, bf16* __restrict__ w2T,
    const float* __restrict__ xin, float* __restrict__ xc, bf16* __restrict__ xb,
    const float* __restrict__ coords,
    const float* __restrict__ rot_w1, const float* __restrict__ rot_b1,
    const float* __restrict__ rot_w2, const float* __restrict__ rot_b2,
    const float* __restrict__ trans_w1, const float* __restrict__ trans_b1,
    const float* __restrict__ trans_w2, const float* __restrict__ trans_b2,
    const float* __restrict__ refl_w1, const float* __restrict__ refl_b1,
    const float* __restrict__ refl_w2, const float* __restrict__ refl_b2,
    float* __restrict__ table,
    const float* __restrict__ fc_b, float* __restrict__ out,
    float* __restrict__ pooled)
{
    const int blk = blockIdx.x, tid = threadIdx.x;
    if (blk < 1408) {
        const float* src; bf16* dst; int C, R, r0, c0;
        if (blk < 384) {
            int z = blk >> 6, rem = blk & 63;
            int l = z / 3, wsel = z % 3;
            src = (wsel == 0 ? Wq : wsel == 1 ? Wk : Wv) + (long)l * ND * ND;
            dst = wqkvT + (long)l * 3 * ND * ND + (long)wsel * ND * ND;
            C = ND; R = ND; r0 = (rem >> 3) * 64; c0 = (rem & 7) * 64;
        } else if (blk < 896) {
            int t = blk - 384, l = t >> 8, rem = t & 255;
            src = ffn_w1 + (long)l * ND * NF;
            dst = w1T + (long)l * NF * ND;
            C = NF; R = ND; r0 = (rem >> 5) * 64; c0 = (rem & 31) * 64;
        } else {
            int t = blk - 896, l = t >> 8, rem = t & 255;
            src = ffn_w2 + (long)l * NF * ND;
            dst = w2T + (long)l * ND * NF;
            C = ND; R = NF; r0 = (rem >> 3) * 64; c0 = (rem & 7) * 64;
        }
        __shared__ float t[64][65];
        const int lx = tid & 15, ly = tid >> 4;    // lx: 16 x 4-wide, ly: 16 rows
        #pragma unroll
        for (int p = 0; p < 4; ++p) {
            const int rr = ly + p * 16;
            float4 v = *(const float4*)(src + (long)(r0 + rr) * C + c0 + lx * 4);
            t[rr][lx * 4 + 0] = v.x; t[rr][lx * 4 + 1] = v.y;
            t[rr][lx * 4 + 2] = v.z; t[rr][lx * 4 + 3] = v.w;
        }
        __syncthreads();
        #pragma unroll
        for (int p = 0; p < 4; ++p) {
            const int cc = ly + p * 16;
            uint2 o;
            o.x = f2bfu(t[lx * 4 + 0][cc]) | (f2bfu(t[lx * 4 + 1][cc]) << 16);
            o.y = f2bfu(t[lx * 4 + 2][cc]) | (f2bfu(t[lx * 4 + 3][cc]) << 16);
            *(uint2*)(dst + (long)(c0 + cc) * R + r0 + lx * 4) = o;
        }
        return;
    }
    if (blk < 2432) {
        long i = (long)(blk - 1408) * 256 + tid;
        float4 v = ((const float4*)xin)[i];
        ((float4*)xc)[i] = v;
        uint2 o;
        o.x = f2bfu(v.x) | (f2bfu(v.y) << 16);
        o.y = f2bfu(v.z) | (f2bfu(v.w) << 16);
        ((uint2*)xb)[i] = o;
        return;
    }
    if (blk < 2448) {
        int idx = (blk - 2432) * 256 + tid;
        if (idx >= 63 * 63) return;
        int da = idx / 63 - 31, db = idx % 63 - 31;
        int ai = da < 0 ? -da : 0, bi = db < 0 ? -db : 0;
        int i = ai * 32 + bi, j = (ai + da) * 32 + (bi + db);
        float2 ci = ((const float2*)coords)[i];
        float2 cj = ((const float2*)coords)[j];
        float dx = cj.x - ci.x, dy = cj.y - ci.y;
        float dist = sqrtf(dx * dx + dy * dy + 1e-8f);
        float th = atan2f(dy, dx);
        float sn = sinf(th), cs = cosf(th);
        #pragma unroll
        for (int l = 0; l < NLAYER; ++l) {
            const float* rw1 = rot_w1 + l * 3 * NH;
            const float* rb1 = rot_b1 + l * NH;
            const float* rw2 = rot_w2 + l * NH;
            const float* tw1 = trans_w1 + l * 2 * NH;
            const float* tb1 = trans_b1 + l * NH;
            const float* tw2 = trans_w2 + l * NH;
            const float* fw1 = refl_w1 + l * 4 * NH;
            const float* fb1 = refl_b1 + l * NH;
            const float* fw2 = refl_w2 + l * NH;
            float acc = rot_b2[l] + trans_b2[l] + refl_b2[l];
            #pragma unroll 8
            for (int h = 0; h < NH; ++h) {
                float hr = fmaxf(dist * rw1[h] + sn * rw1[NH + h] + cs * rw1[2 * NH + h] + rb1[h], 0.f);
                acc += hr * rw2[h];
                float ht = fmaxf(dx * tw1[h] + dy * tw1[NH + h] + tb1[h], 0.f);
                acc += ht * tw2[h];
                float hf = fmaxf(dx * fw1[h] + dy * fw1[NH + h] - dx * fw1[2 * NH + h] - dy * fw1[3 * NH + h] + fb1[h], 0.f);
                acc += hf * fw2[h];
            }
            table[l * 3969 + idx] = acc;
        }
        return;
    }
    {
        int i = (blk - 2448) * 256 + tid;
        if (i < NB * NC) out[i] = fc_b[i % NC];
        int j = i - NB * NC;
        if (j >= 0 && j < NB * ND) pooled[j] = 0.f;
    }
}

// ---------------------------------------------------------------------------
// Row softmax over NS=1024 (f32 in) -> bf16 out
// ---------------------------------------------------------------------------
__global__ __launch_bounds__(256) void softmax_kernel(
    const float* __restrict__ sc, bf16* __restrict__ P)
{
    const float* p = sc + (long)blockIdx.x * NS;
    const int tid = threadIdx.x;
    float4 v = ((const float4*)p)[tid];
    float m = fmaxf(fmaxf(v.x, v.y), fmaxf(v.z, v.w));
    #pragma unroll
    for (int off = 32; off; off >>= 1) m = fmaxf(m, __shfl_xor(m, off));
    __shared__ float red[4], red2[4];
    int wid = tid >> 6;
    if ((tid & 63) == 0) red[wid] = m;
    __syncthreads();
    m = fmaxf(fmaxf(red[0], red[1]), fmaxf(red[2], red[3]));
    v.x = __expf(v.x - m); v.y = __expf(v.y - m);
    v.z = __expf(v.z - m); v.w = __expf(v.w - m);
    float s = v.x + v.y + v.z + v.w;
    #pragma unroll
    for (int off = 32; off; off >>= 1) s += __shfl_xor(s, off);
    if ((tid & 63) == 0) red2[wid] = s;
    __syncthreads();
    s = red2[0] + red2[1] + red2[2] + red2[3];
    float inv = 1.f / s;
    uint2 o;
    o.x = f2bfu(v.x * inv) | (f2bfu(v.y * inv) << 16);
    o.y = f2bfu(v.z * inv) | (f2bfu(v.w * inv) << 16);
    ((uint2*)(P + (long)blockIdx.x * NS))[tid] = o;
}

// ---------------------------------------------------------------------------
// out = LayerNorm(x (+res)); also writes bf16 copy if outb != null
// ---------------------------------------------------------------------------
__global__ __launch_bounds__(256) void add_ln_kernel(
    const float* __restrict__ x, const float* __restrict__ res,
    const float* __restrict__ g, const float* __restrict__ bt,
    float* __restrict__ out, bf16* __restrict__ outb)
{
    long row = blockIdx.x;
    const int tid = threadIdx.x;
    float2 xv = ((const float2*)(x + row * ND))[tid];
    if (res) {
        float2 rv = ((const float2*)(res + row * ND))[tid];
        xv.x += rv.x; xv.y += rv.y;
    }
    float s = xv.x + xv.y;
    float ss = xv.x * xv.x + xv.y * xv.y;
    #pragma unroll
    for (int off = 32; off; off >>= 1) {
        s += __shfl_xor(s, off);
        ss += __shfl_xor(ss, off);
    }
    __shared__ float rs[4], rss[4];
    int wid = tid >> 6;
    if ((tid & 63) == 0) { rs[wid] = s; rss[wid] = ss; }
    __syncthreads();
    s = rs[0] + rs[1] + rs[2] + rs[3];
    ss = rss[0] + rss[1] + rss[2] + rss[3];
    float mu = s * (1.f / ND);
    float var = ss * (1.f / ND) - mu * mu;
    float inv = rsqrtf(var + EPS_LN);
    float2 gv = ((const float2*)g)[tid];
    float2 bv = ((const float2*)bt)[tid];
    float2 o;
    o.x = (xv.x - mu) * inv * gv.x + bv.x;
    o.y = (xv.y - mu) * inv * gv.y + bv.y;
    ((float2*)(out + row * ND))[tid] = o;
    if (outb)
        ((unsigned int*)(outb + row * ND))[tid] =
            f2bfu(o.x) | (f2bfu(o.y) << 16);
}

// ---------------------------------------------------------------------------
// pooled[b][d] += sum over 16 contiguous rows / NS; 128 blocks, atomics.
// ---------------------------------------------------------------------------
__global__ __launch_bounds__(256) void pool_kernel(
    const float* __restrict__ x, float* __restrict__ pooled)
{
    const int tid = threadIdx.x;
    const long row0 = (long)blockIdx.x * 16;
    const int b = (int)(row0 >> 10);
    float ax = 0.f, ay = 0.f, az = 0.f, aw = 0.f;
    #pragma unroll
    for (int it = 0; it < 8; ++it) {
        long r = row0 + it * 2 + (tid >> 7);
        float4 v = ((const float4*)(x + r * ND))[tid & 127];
        ax += v.x; ay += v.y; az += v.z; aw += v.w;
    }
    __shared__ float red[256][4];
    red[tid][0] = ax; red[tid][1] = ay; red[tid][2] = az; red[tid][3] = aw;
    __syncthreads();
    if (tid < 128) {
        int d = tid * 4;
        atomicAdd(&pooled[b * ND + d + 0], (red[tid][0] + red[tid + 128][0]) * (1.f / NS));
        atomicAdd(&pooled[b * ND + d + 1], (red[tid][1] + red[tid + 128][1]) * (1.f / NS));
        atomicAdd(&pooled[b * ND + d + 2], (red[tid][2] + red[tid + 128][2]) * (1.f / NS));
        atomicAdd(&pooled[b * ND + d + 3], (red[tid][3] + red[tid + 128][3]) * (1.f / NS));
    }
}

// ---------------------------------------------------------------------------
// out[b][c] += partial dot over 64-wide d-chunk; grid (16, NB, 8), atomics.
// ---------------------------------------------------------------------------
__global__ __launch_bounds__(256) void fc_kernel(
    const float* __restrict__ pooled, const float* __restrict__ w,
    float* __restrict__ out)
{
    const int lane = threadIdx.x & 63, dg = threadIdx.x >> 6;
    const int c = blockIdx.x * 64 + lane;
    const int b = blockIdx.y;
    const int d0 = blockIdx.z * 64 + dg * 16;
    const bool ok = (c < NC);
    const float* p = pooled + b * ND;
    float acc = 0.f;
    #pragma unroll
    for (int d = 0; d < 16; ++d)
        acc += p[d0 + d] * (ok ? w[(long)(d0 + d) * NC + c] : 0.f);
    __shared__ float red[4][64];
    red[dg][lane] = acc;
    __syncthreads();
    if (dg == 0 && ok)
        atomicAdd(&out[(long)b * NC + c],
                  red[0][lane] + red[1][lane] + red[2][lane] + red[3][lane]);
}

// ---------------------------------------------------------------------------
extern "C" void kernel_launch(void* const* d_in, const int* in_sizes, int n_in,
                              void* d_out, int out_size, void* d_ws, size_t ws_size,
                              hipStream_t stream)
{
    const float* x_in   = (const float*)d_in[0];
    const float* coords = (const float*)d_in[1];
    const float* Wq     = (const float*)d_in[2];
    const float* Wk     = (const float*)d_in[3];
    const float* Wv     = (const float*)d_in[4];
    const float* rot_w1 = (const float*)d_in[5];
    const float* rot_b1 = (const float*)d_in[6];
    const float* rot_w2 = (const float*)d_in[7];
    const float* rot_b2 = (const float*)d_in[8];
    const float* trans_w1 = (const float*)d_in[9];
    const float* trans_b1 = (const float*)d_in[10];
    const float* trans_w2 = (const float*)d_in[11];
    const float* trans_b2 = (const float*)d_in[12];
    const float* refl_w1 = (const float*)d_in[13];
    const float* refl_b1 = (const float*)d_in[14];
    const float* refl_w2 = (const float*)d_in[15];
    const float* refl_b2 = (const float*)d_in[16];
    const float* ln1_g = (const float*)d_in[17];
    const float* ln1_b = (const float*)d_in[18];
    const float* ffn_w1 = (const float*)d_in[19];
    const float* ffn_b1 = (const float*)d_in[20];
    const float* ffn_w2 = (const float*)d_in[21];
    const float* ffn_b2 = (const float*)d_in[22];
    const float* ln2_g = (const float*)d_in[23];
    const float* ln2_b = (const float*)d_in[24];
    const float* lnf_g = (const float*)d_in[25];
    const float* lnf_b = (const float*)d_in[26];
    const float* fc_w = (const float*)d_in[27];
    const float* fc_b = (const float*)d_in[28];
    float* out = (float*)d_out;

    const long XSZ = (long)NB * NS * ND;
    const long SSZ = (long)NB * NS * NS;

    char* wp = (char*)d_ws;
    auto alloc = [&](long bytes) -> char* {
        char* p = wp; wp += (bytes + 255) & ~(long)255; return p;
    };
    float* x_cur  = (float*)alloc(XSZ * 4);
    bf16*  xb     = (bf16*)alloc(XSZ * 2);
    bf16*  qkv    = (bf16*)alloc((long)NB * NS * 1536 * 2);
    bf16*  vT     = (bf16*)alloc((long)NB * ND * NS * 2);
    float* sc     = (float*)alloc(SSZ * 4);
    bf16*  pb     = (bf16*)alloc(SSZ * 2);
    float* ao     = (float*)alloc(XSZ * 4);
    bf16*  hfb    = (bf16*)alloc((long)NB * NS * NF * 2);
    bf16*  wqkvT  = (bf16*)alloc((long)NLAYER * 3 * ND * ND * 2);
    bf16*  w1T    = (bf16*)alloc((long)NLAYER * NF * ND * 2);
    bf16*  w2T    = (bf16*)alloc((long)NLAYER * ND * NF * 2);
    float* table  = (float*)alloc((long)NLAYER * 3969 * 4);
    float* pooled = (float*)alloc((long)NB * ND * 4);

    const float inv_scale = 1.0f / sqrtf((float)ND);
    const long QKVLD = 1536;

    prep_kernel<<<dim3(2460), 256, 0, stream>>>(
        Wq, Wk, Wv, ffn_w1, ffn_w2, wqkvT, w1T, w2T,
        x_in, x_cur, xb, coords,
        rot_w1, rot_b1, rot_w2, rot_b2,
        trans_w1, trans_b1, trans_w2, trans_b2,
        refl_w1, refl_b1, refl_w2, refl_b2, table,
        fc_b, out, pooled);

    for (int l = 0; l < NLAYER; ++l) {
        // QKV: [2048,512]@[1536,512]^T -> qkv bf16 (V cols also -> vT)
        mfma_gemm<64, 128, 2, 4, true, false, false, true>
            <<<dim3(1536 / 128, (NB * NS) / 64, 1), 512, 0, stream>>>(
            xb, wqkvT + (long)l * 3 * ND * ND, nullptr, qkv, nullptr, vT,
            ND, ND, ND, QKVLD, 0, 0, 0, 0.f);

        // scores = QK^T * inv_scale + table -> f32
        mfma_gemm<64, 128, 2, 4, false, false, true, false>
            <<<dim3(NS / 128, NS / 64, NB), 512, 0, stream>>>(
            qkv, qkv + ND, nullptr, sc, table + (long)l * 3969, nullptr,
            ND, QKVLD, QKVLD, NS, (long)NS * QKVLD, (long)NS * QKVLD,
            (long)NS * NS, inv_scale);

        softmax_kernel<<<dim3(NB * NS), 256, 0, stream>>>(sc, pb);

        // attn_out = P @ V
        mfma_gemm<64, 64, 4, 2, false, false, false, false>
            <<<dim3(ND / 64, NS / 64, NB), 512, 0, stream>>>(
            pb, vT, nullptr, ao, nullptr, nullptr,
            NS, NS, NS, ND, (long)NS * NS, (long)ND * NS, (long)NS * ND, 0.f);

        add_ln_kernel<<<dim3(NB * NS), 256, 0, stream>>>(
            x_cur, ao, ln1_g + (long)l * ND, ln1_b + (long)l * ND, x_cur, xb);

        // FFN1
        mfma_gemm<128, 128, 4, 2, true, true, false, false>
            <<<dim3(NF / 128, (NB * NS) / 128, 1), 512, 0, stream>>>(
            xb, w1T + (long)l * NF * ND, ffn_b1 + (long)l * NF, hfb, nullptr, nullptr,
            ND, ND, ND, NF, 0, 0, 0, 0.f);

        // FFN2
        mfma_gemm<64, 64, 4, 2, false, false, false, false>
            <<<dim3(ND / 64, (NB * NS) / 64, 1), 512, 0, stream>>>(
            hfb, w2T + (long)l * ND * NF, ffn_b2 + (long)l * ND, ao, nullptr, nullptr,
            NF, NF, NF, ND, 0, 0, 0, 0.f);

        add_ln_kernel<<<dim3(NB * NS), 256, 0, stream>>>(
            x_cur, ao, ln2_g + (long)l * ND, ln2_b + (long)l * ND, x_cur, xb);
    }

    add_ln_kernel<<<dim3(NB * NS), 256, 0, stream>>>(
        x_cur, nullptr, lnf_g, lnf_b, x_cur, nullptr);

    pool_kernel<<<dim3((NB * NS) / 16), 256, 0, stream>>>(x_cur, pooled);

    fc_kernel<<<dim3((NC + 63) / 64, NB, ND / 64), 256, 0, stream>>>(pooled, fc_w, out);
}